// Round 1
// baseline (341.243 us; speedup 1.0000x reference)
//
#include <hip/hip_runtime.h>
#include <hip/hip_bf16.h>
#include <stdint.h>

using bf16 = __hip_bfloat16;
typedef __attribute__((ext_vector_type(8))) short short8;     // 8 bf16 MFMA frag
typedef __attribute__((ext_vector_type(4))) float f32x4;      // MFMA acc
typedef __attribute__((ext_vector_type(4))) float float4v;
typedef __attribute__((ext_vector_type(4))) unsigned short us4;

#define LDS_U32 __attribute__((address_space(3))) uint32_t
#define GLB_U32 __attribute__((address_space(1))) uint32_t

__device__ __forceinline__ unsigned short f2b(float f) {
  union { float f; uint32_t u; } x; x.f = f;
  uint32_t r = x.u + 0x7FFFu + ((x.u >> 16) & 1u);  // RNE
  return (unsigned short)(r >> 16);
}

// ---------------- fp32 -> bf16 cast, up to 4 arrays in one launch ----------------
__global__ void cast_multi(const float* __restrict__ s0, const float* __restrict__ s1,
                           const float* __restrict__ s2, const float* __restrict__ s3,
                           bf16* __restrict__ d0, bf16* __restrict__ d1,
                           bf16* __restrict__ d2, bf16* __restrict__ d3,
                           int nvec, int narr) {
  int total = nvec * narr;
  for (int i = blockIdx.x * blockDim.x + threadIdx.x; i < total;
       i += gridDim.x * blockDim.x) {
    int a = i / nvec, vi = i - a * nvec;
    const float* s = (a == 0) ? s0 : (a == 1) ? s1 : (a == 2) ? s2 : s3;
    bf16* d = (a == 0) ? d0 : (a == 1) ? d1 : (a == 2) ? d2 : d3;
    float4v x = ((const float4v*)s)[vi];
    us4 y;
    y.x = f2b(x.x); y.y = f2b(x.y); y.z = f2b(x.z); y.w = f2b(x.w);
    ((us4*)d)[vi] = y;
  }
}

// ---------------- GEMM: C[M,N] = A[M,K] * B[N,K]^T, bf16 in, fp32 acc ----------------
// OUT_MODE 0: bf16 row-major [M,N]; 1: fp32 row-major [M,N];
// OUT_MODE 2: bf16 transposed per-head Vt[(b*1024 + n)][2048] at s = m&2047
template <int OUT_MODE>
__global__ __launch_bounds__(256, 2)
void gemm_bt(const bf16* __restrict__ A, const bf16* __restrict__ B,
             void* __restrict__ Cv, int M, int N, int K) {
  __shared__ bf16 Alds[128 * 64];
  __shared__ bf16 Blds[128 * 64];
  const int t = threadIdx.x;
  const int lane = t & 63, wave = t >> 6;
  const int l15 = lane & 15, l4 = lane >> 4;
  const int m0 = blockIdx.y * 128, n0 = blockIdx.x * 128;
  const int wr = (wave >> 1) * 64, wc = (wave & 1) * 64;

  f32x4 acc[4][4] = {};

  for (int kt = 0; kt < K; kt += 64) {
#pragma unroll
    for (int i = 0; i < 4; ++i) {
      int f = i * 256 + t;
      int row = f >> 3;
      int csrc = (f & 7) ^ (row & 7);  // inverse XOR-swizzle on the global source
      __builtin_amdgcn_global_load_lds(
          (const GLB_U32*)(A + (size_t)(m0 + row) * K + kt + csrc * 8),
          (LDS_U32*)(Alds + f * 8), 16, 0, 0);
      __builtin_amdgcn_global_load_lds(
          (const GLB_U32*)(B + (size_t)(n0 + row) * K + kt + csrc * 8),
          (LDS_U32*)(Blds + f * 8), 16, 0, 0);
    }
    __syncthreads();
#pragma unroll
    for (int ks = 0; ks < 2; ++ks) {
      short8 af[4], bfr[4];
#pragma unroll
      for (int mi = 0; mi < 4; ++mi) {
        int row = wr + mi * 16 + l15;
        int ch = (ks * 4 + l4) ^ (row & 7);  // swizzled read
        af[mi] = *(const short8*)(Alds + row * 64 + ch * 8);
      }
#pragma unroll
      for (int ni = 0; ni < 4; ++ni) {
        int row = wc + ni * 16 + l15;
        int ch = (ks * 4 + l4) ^ (row & 7);
        bfr[ni] = *(const short8*)(Blds + row * 64 + ch * 8);
      }
#pragma unroll
      for (int mi = 0; mi < 4; ++mi)
#pragma unroll
        for (int ni = 0; ni < 4; ++ni)
          acc[mi][ni] = __builtin_amdgcn_mfma_f32_16x16x32_bf16(
              af[mi], bfr[ni], acc[mi][ni], 0, 0, 0);
    }
    __syncthreads();
  }

#pragma unroll
  for (int mi = 0; mi < 4; ++mi) {
#pragma unroll
    for (int ni = 0; ni < 4; ++ni) {
      int rbase = m0 + wr + mi * 16 + l4 * 4;      // 4 consecutive rows
      int col = n0 + wc + ni * 16 + l15;
      if constexpr (OUT_MODE == 0) {
        unsigned short* C = (unsigned short*)Cv;
#pragma unroll
        for (int r = 0; r < 4; ++r)
          C[(size_t)(rbase + r) * N + col] = f2b(acc[mi][ni][r]);
      } else if constexpr (OUT_MODE == 1) {
        float* C = (float*)Cv;
#pragma unroll
        for (int r = 0; r < 4; ++r)
          C[(size_t)(rbase + r) * N + col] = acc[mi][ni][r];
      } else {
        // Vt[b][h][d][s]: addr = (b*1024 + col)*2048 + s, 4 consecutive s
        unsigned short* C = (unsigned short*)Cv;
        int b = rbase >> 11, s = rbase & 2047;
        size_t addr = ((size_t)(b * 1024 + col)) * 2048 + s;
        us4 y;
        y.x = f2b(acc[mi][ni][0]); y.y = f2b(acc[mi][ni][1]);
        y.z = f2b(acc[mi][ni][2]); y.w = f2b(acc[mi][ni][3]);
        *(us4*)(C + addr) = y;
      }
    }
  }
}

// ---------------- causal flash attention ----------------
// Q,K: bf16 [B*S, 1024] (head h at cols h*64..); Vt: bf16 [B*H][64][2048];
// O: bf16 [B*S, 1024]. Grid (S/128, H, B), 256 thr = 4 independent waves (32 q-rows each).
__global__ __launch_bounds__(256, 2)
void attn_fwd(const bf16* __restrict__ Q, const bf16* __restrict__ K,
              const bf16* __restrict__ Vt, const int* __restrict__ mask,
              bf16* __restrict__ O) {
  const int b = blockIdx.z, h = blockIdx.y, qt = blockIdx.x;
  const int t = threadIdx.x, wave = t >> 6, lane = t & 63;
  const int l15 = lane & 15, l4 = lane >> 4;
  const int q0 = qt * 128 + wave * 32;

  __shared__ bf16 PldsAll[4][32 * 72];  // +16B row pad: 144B stride, conflict-free b128
  bf16* Plds = PldsAll[wave];

  const size_t bqk = (size_t)b * 2048 * 1024 + h * 64;

  short8 qa[2][2];
#pragma unroll
  for (int qm = 0; qm < 2; ++qm)
#pragma unroll
    for (int ks = 0; ks < 2; ++ks)
      qa[qm][ks] = *(const short8*)(Q + bqk + (size_t)(q0 + qm * 16 + l15) * 1024 +
                                    ks * 32 + l4 * 8);

  f32x4 acc[2][4] = {};
  float mrun[2][4], lrun[2][4];
#pragma unroll
  for (int qm = 0; qm < 2; ++qm)
#pragma unroll
    for (int r = 0; r < 4; ++r) { mrun[qm][r] = -1e30f; lrun[qm][r] = 0.f; }

  const size_t vbase = (size_t)(b * 16 + h) * 64 * 2048;
  const int mbase = b * 2048;
  const int kmax = q0 + 32;  // causal: this wave needs k <= q0+31

  for (int k0 = 0; k0 < kmax; k0 += 64) {
    short8 kb[4][2];
#pragma unroll
    for (int kn = 0; kn < 4; ++kn)
#pragma unroll
      for (int ks = 0; ks < 2; ++ks)
        kb[kn][ks] = *(const short8*)(K + bqk + (size_t)(k0 + kn * 16 + l15) * 1024 +
                                      ks * 32 + l4 * 8);

    f32x4 sc[2][4] = {};
#pragma unroll
    for (int ks = 0; ks < 2; ++ks)
#pragma unroll
      for (int qm = 0; qm < 2; ++qm)
#pragma unroll
        for (int kn = 0; kn < 4; ++kn)
          sc[qm][kn] = __builtin_amdgcn_mfma_f32_16x16x32_bf16(
              qa[qm][ks], kb[kn][ks], sc[qm][kn], 0, 0, 0);

    int mv[4];
#pragma unroll
    for (int kn = 0; kn < 4; ++kn) mv[kn] = mask[mbase + k0 + kn * 16 + l15];

    float x[2][4][4];
#pragma unroll
    for (int qm = 0; qm < 2; ++qm)
#pragma unroll
      for (int kn = 0; kn < 4; ++kn) {
        int kg = k0 + kn * 16 + l15;
#pragma unroll
        for (int r = 0; r < 4; ++r) {
          int qg = q0 + qm * 16 + l4 * 4 + r;
          float vv = sc[qm][kn][r] * 0.125f;
          x[qm][kn][r] = (mv[kn] == 0 || kg > qg) ? -1e9f : vv;
        }
      }

#pragma unroll
    for (int qm = 0; qm < 2; ++qm)
#pragma unroll
      for (int r = 0; r < 4; ++r) {
        float mx = fmaxf(fmaxf(x[qm][0][r], x[qm][1][r]),
                         fmaxf(x[qm][2][r], x[qm][3][r]));
        mx = fmaxf(mx, __shfl_xor(mx, 1));
        mx = fmaxf(mx, __shfl_xor(mx, 2));
        mx = fmaxf(mx, __shfl_xor(mx, 4));
        mx = fmaxf(mx, __shfl_xor(mx, 8));
        float mnew = fmaxf(mrun[qm][r], mx);
        float corr = __expf(mrun[qm][r] - mnew);
        mrun[qm][r] = mnew;
        float rs = 0.f;
#pragma unroll
        for (int kn = 0; kn < 4; ++kn) {
          float p = __expf(x[qm][kn][r] - mnew);
          x[qm][kn][r] = p;
          rs += p;
        }
        rs += __shfl_xor(rs, 1);
        rs += __shfl_xor(rs, 2);
        rs += __shfl_xor(rs, 4);
        rs += __shfl_xor(rs, 8);
        lrun[qm][r] = lrun[qm][r] * corr + rs;
#pragma unroll
        for (int nd = 0; nd < 4; ++nd) acc[qm][nd][r] *= corr;
      }

    // P (D-layout) -> LDS -> A-frag layout
#pragma unroll
    for (int qm = 0; qm < 2; ++qm)
#pragma unroll
      for (int kn = 0; kn < 4; ++kn)
#pragma unroll
        for (int r = 0; r < 4; ++r)
          ((unsigned short*)Plds)[(qm * 16 + l4 * 4 + r) * 72 + kn * 16 + l15] =
              f2b(x[qm][kn][r]);

#pragma unroll
    for (int ks = 0; ks < 2; ++ks) {
      short8 pa[2], vb[4];
#pragma unroll
      for (int qm = 0; qm < 2; ++qm)
        pa[qm] = *(const short8*)(Plds + (qm * 16 + l15) * 72 + ks * 32 + l4 * 8);
#pragma unroll
      for (int nd = 0; nd < 4; ++nd)
        vb[nd] = *(const short8*)(Vt + vbase + (size_t)(nd * 16 + l15) * 2048 +
                                  k0 + ks * 32 + l4 * 8);
#pragma unroll
      for (int qm = 0; qm < 2; ++qm)
#pragma unroll
        for (int nd = 0; nd < 4; ++nd)
          acc[qm][nd] = __builtin_amdgcn_mfma_f32_16x16x32_bf16(
              pa[qm], vb[nd], acc[qm][nd], 0, 0, 0);
    }
  }

  float inv[2][4];
#pragma unroll
  for (int qm = 0; qm < 2; ++qm)
#pragma unroll
    for (int r = 0; r < 4; ++r) inv[qm][r] = 1.0f / lrun[qm][r];

#pragma unroll
  for (int qm = 0; qm < 2; ++qm)
#pragma unroll
    for (int nd = 0; nd < 4; ++nd)
#pragma unroll
      for (int r = 0; r < 4; ++r)
        ((unsigned short*)O)[bqk + (size_t)(q0 + qm * 16 + l4 * 4 + r) * 1024 +
                             nd * 16 + l15] = f2b(acc[qm][nd][r] * inv[qm][r]);
}

// ---------------- launch ----------------
extern "C" void kernel_launch(void* const* d_in, const int* in_sizes, int n_in,
                              void* d_out, int out_size, void* d_ws, size_t ws_size,
                              hipStream_t stream) {
  const float* q = (const float*)d_in[0];
  const float* k = (const float*)d_in[1];
  const float* v = (const float*)d_in[2];
  const int* mask = (const int*)d_in[3];
  const float* Wq = (const float*)d_in[4];
  const float* Wk = (const float*)d_in[5];
  const float* Wv = (const float*)d_in[6];
  const float* Wo = (const float*)d_in[7];
  float* out = (float*)d_out;

  const size_t NT = 4096 * 1024;  // tokens x d_model
  const size_t NW = 1024 * 1024;
  bf16* p = (bf16*)d_ws;
  bf16* qb = p;  p += NT;
  bf16* kb = p;  p += NT;
  bf16* vb = p;  p += NT;
  bf16* Wqb = p; p += NW;
  bf16* Wkb = p; p += NW;
  bf16* Wvb = p; p += NW;
  bf16* Wob = p; p += NW;
  bf16* Qh = p;  p += NT;
  bf16* Kh = p;  p += NT;
  bf16* Vt = p;  p += NT;
  bf16* Oh = p;  p += NT;

  cast_multi<<<2048, 256, 0, stream>>>(q, k, v, nullptr, qb, kb, vb, nullptr,
                                       (int)(NT / 4), 3);
  cast_multi<<<1024, 256, 0, stream>>>(Wq, Wk, Wv, Wo, Wqb, Wkb, Wvb, Wob,
                                       (int)(NW / 4), 4);
  dim3 gg(8, 32);
  gemm_bt<0><<<gg, 256, 0, stream>>>(qb, Wqb, Qh, 4096, 1024, 1024);
  gemm_bt<0><<<gg, 256, 0, stream>>>(kb, Wkb, Kh, 4096, 1024, 1024);
  gemm_bt<2><<<gg, 256, 0, stream>>>(vb, Wvb, Vt, 4096, 1024, 1024);
  attn_fwd<<<dim3(16, 16, 2), 256, 0, stream>>>(Qh, Kh, Vt, mask, Oh);
  gemm_bt<1><<<gg, 256, 0, stream>>>(Oh, Wob, out, 4096, 1024, 1024);
}